// Round 15
// baseline (11513.572 us; speedup 1.0000x reference)
//
#include <hip/hip_runtime.h>
#include <cstddef>

constexpr int kB = 2;
constexpr int kN = 16384;
constexpr int kC = 64;
constexpr int kS = 4096;    // NPOINT
constexpr int kNS = 32;     // NSAMPLE
constexpr int kNC16 = 1024; // 16-point chunks per batch
constexpr int kNP = kN / 2; // point pairs per batch

typedef float f32x2 __attribute__((ext_vector_type(2)));

__device__ __forceinline__ unsigned expand10(unsigned v) {
  v &= 1023u;
  v = (v | (v << 16)) & 0x030000FFu;
  v = (v | (v <<  8)) & 0x0300F00Fu;
  v = (v | (v <<  4)) & 0x030C30C3u;
  v = (v | (v <<  2)) & 0x09249249u;
  return v;
}

template <int C>
__device__ __forceinline__ unsigned dpp_u32(unsigned x) {
  return (unsigned)__builtin_amdgcn_update_dpp((int)x, (int)x, C, 0xF, 0xF, false);
}
__device__ __forceinline__ unsigned max8(unsigned x) {
  x = max(x, dpp_u32<0xB1>(x));   // quad_perm [1,0,3,2]
  x = max(x, dpp_u32<0x4E>(x));   // quad_perm [2,3,0,1]
  x = max(x, dpp_u32<0x141>(x));  // row_half_mirror
  return x;
}
template <int C>
__device__ __forceinline__ void u64max_dpp(unsigned& hi, unsigned& lo) {
  unsigned h2 = dpp_u32<C>(hi), l2 = dpp_u32<C>(lo);
  bool g = (h2 > hi) || (h2 == hi && l2 > lo);
  hi = g ? h2 : hi;
  lo = g ? l2 : lo;
}

#define PK_ADD(d, a, b) asm("v_pk_add_f32 %0, %1, %2" : "=v"(d) : "v"(a), "v"(b))
#define PK_MUL(d, a, b) asm("v_pk_mul_f32 %0, %1, %2" : "=v"(d) : "v"(a), "v"(b))

// -------- transpose [b][Cdim][Ndim] -> [b][Ndim][Cdim], 32x32 tiles --------
__global__ void transpose_kernel(const float* __restrict__ in,
                                 float* __restrict__ out,
                                 int Cdim, int Ndim) {
  __shared__ float tile[32][33];
  int b = blockIdx.z;
  int n0 = blockIdx.x * 32;
  int c0 = blockIdx.y * 32;
  int tx = threadIdx.x;
  const float* inb = in + (size_t)b * Cdim * Ndim;
  float* outb = out + (size_t)b * Cdim * Ndim;
#pragma unroll
  for (int i = threadIdx.y; i < 32; i += 8)
    tile[i][tx] = inb[(size_t)(c0 + i) * Ndim + (n0 + tx)];
  __syncthreads();
#pragma unroll
  for (int i = threadIdx.y; i < 32; i += 8)
    outb[(size_t)(n0 + i) * Cdim + (c0 + tx)] = tile[tx][i];
}

// -------- FPS prep (unchanged R9-R13) + progress zeroing --------
__global__ __launch_bounds__(1024) void fps_prep_kernel(
    const float* __restrict__ xyz, float* __restrict__ pxx,
    float* __restrict__ pxy, float* __restrict__ pxz,
    unsigned* __restrict__ pxo, float* __restrict__ aabb,
    unsigned* __restrict__ prog) {
  const int b = blockIdx.x;
  const int t = threadIdx.x;
  const int lane = t & 63;
  const int w = t >> 6;
  if (t == 0)
    __hip_atomic_store(&prog[b], 0u, __ATOMIC_RELEASE, __HIP_MEMORY_SCOPE_AGENT);
  const float* P = xyz + (size_t)b * kN * 3;
  __shared__ unsigned long long keys[kN];   // 128 KB
  __shared__ float sbb[6][16];

  float mnx = 3e38f, mny = 3e38f, mnz = 3e38f;
  float mxx = -3e38f, mxy = -3e38f, mxz = -3e38f;
  for (int p = t; p < kN; p += 1024) {
    float x = P[p * 3], y = P[p * 3 + 1], z = P[p * 3 + 2];
    mnx = fminf(mnx, x); mny = fminf(mny, y); mnz = fminf(mnz, z);
    mxx = fmaxf(mxx, x); mxy = fmaxf(mxy, y); mxz = fmaxf(mxz, z);
  }
#pragma unroll
  for (int off = 32; off >= 1; off >>= 1) {
    mnx = fminf(mnx, __shfl_xor(mnx, off, 64));
    mny = fminf(mny, __shfl_xor(mny, off, 64));
    mnz = fminf(mnz, __shfl_xor(mnz, off, 64));
    mxx = fmaxf(mxx, __shfl_xor(mxx, off, 64));
    mxy = fmaxf(mxy, __shfl_xor(mxy, off, 64));
    mxz = fmaxf(mxz, __shfl_xor(mxz, off, 64));
  }
  if (lane == 0) {
    sbb[0][w] = mnx; sbb[1][w] = mny; sbb[2][w] = mnz;
    sbb[3][w] = mxx; sbb[4][w] = mxy; sbb[5][w] = mxz;
  }
  __syncthreads();
  mnx = sbb[0][lane & 15]; mny = sbb[1][lane & 15]; mnz = sbb[2][lane & 15];
  mxx = sbb[3][lane & 15]; mxy = sbb[4][lane & 15]; mxz = sbb[5][lane & 15];
#pragma unroll
  for (int off = 8; off >= 1; off >>= 1) {
    mnx = fminf(mnx, __shfl_xor(mnx, off, 64));
    mny = fminf(mny, __shfl_xor(mny, off, 64));
    mnz = fminf(mnz, __shfl_xor(mnz, off, 64));
    mxx = fmaxf(mxx, __shfl_xor(mxx, off, 64));
    mxy = fmaxf(mxy, __shfl_xor(mxy, off, 64));
    mxz = fmaxf(mxz, __shfl_xor(mxz, off, 64));
  }
  __syncthreads();
  const float sx = 1023.0f / fmaxf(mxx - mnx, 1e-20f);
  const float sy = 1023.0f / fmaxf(mxy - mny, 1e-20f);
  const float sz = 1023.0f / fmaxf(mxz - mnz, 1e-20f);
  for (int p = t; p < kN; p += 1024) {
    float x = P[p * 3], y = P[p * 3 + 1], z = P[p * 3 + 2];
    int qx = (int)((x - mnx) * sx); qx = max(0, min(1023, qx));
    int qy = (int)((y - mny) * sy); qy = max(0, min(1023, qy));
    int qz = (int)((z - mnz) * sz); qz = max(0, min(1023, qz));
    unsigned mort = (expand10((unsigned)qx) << 2) |
                    (expand10((unsigned)qy) << 1) | expand10((unsigned)qz);
    keys[p] = ((unsigned long long)mort << 14) | (unsigned)p;
  }
  __syncthreads();
  for (unsigned k = 2; k <= (unsigned)kN; k <<= 1) {
    for (unsigned j = k >> 1; j > 0; j >>= 1) {
      for (int i = t; i < kN; i += 1024) {
        int l = i ^ (int)j;
        if (l > i) {
          unsigned long long a = keys[i], c = keys[l];
          bool asc = ((i & (int)k) == 0);
          if ((a > c) == asc) { keys[i] = c; keys[l] = a; }
        }
      }
      __syncthreads();
    }
  }
  float* FX = pxx + (size_t)b * kN;
  float* FY = pxy + (size_t)b * kN;
  float* FZ = pxz + (size_t)b * kN;
  unsigned* FO = pxo + (size_t)b * kN;
  for (int i = t; i < kN; i += 1024) {
    int o = (int)(keys[i] & 0x3FFFull);
    int c = i >> 4, j = i & 15;
    int fi = c * 16 + ((j & 7) << 1) + (j >> 3);
    FX[fi] = P[o * 3];
    FY[fi] = P[o * 3 + 1];
    FZ[fi] = P[o * 3 + 2];
    FO[fi] = 16383u - (unsigned)o;   // tie key: max(16383-o) == min orig
  }
  if (t < kNC16) {
    float amn = 3e38f, bmn = 3e38f, cmn = 3e38f;
    float amx = -3e38f, bmx = -3e38f, cmx = -3e38f;
    for (int kk = 0; kk < 16; kk++) {
      int o = (int)(keys[t * 16 + kk] & 0x3FFFull);
      float x = P[o * 3], y = P[o * 3 + 1], z = P[o * 3 + 2];
      amn = fminf(amn, x); amx = fmaxf(amx, x);
      bmn = fminf(bmn, y); bmx = fmaxf(bmx, y);
      cmn = fminf(cmn, z); cmx = fmaxf(cmx, z);
    }
    float* AB = aabb + (size_t)b * 6 * kNC16;
    AB[0 * kNC16 + t] = (amn + amx) * 0.5f;
    AB[1 * kNC16 + t] = (bmn + bmx) * 0.5f;
    AB[2 * kNC16 + t] = (cmn + cmx) * 0.5f;
    AB[3 * kNC16 + t] = (amx - amn) * 0.5f * 1.0001f + 2e-7f;
    AB[4 * kNC16 + t] = (bmx - bmn) * 0.5f * 1.0001f + 2e-7f;
    AB[5 * kNC16 + t] = (cmx - cmn) * 0.5f * 1.0001f + 2e-7f;
  }
}

// -------- FUSED kernel: blocks 0-1 = FPS (R13 verbatim + progress publish);
// blocks 2-255 = consumers (one query per wave: spin on progress, ball query,
// gather+MLP with group_mlp-identical arithmetic, direct out_feat writes).
// Residency: 256 blocks x 1024 thr x 138KB LDS = 1 block/CU -> all resident
// (no deadlock); bounded spin guard converts any logic bug into absmax fail.
// Coherence: fps publishes via agent-scope release store; consumers acquire-
// load progress and read coords via agent-scope atomic loads (G16 pattern).
__global__ __launch_bounds__(1024) void fused_kernel(
    const float* __restrict__ xyz,
    const float* __restrict__ pxx, const float* __restrict__ pxy,
    const float* __restrict__ pxz, const unsigned* __restrict__ pxo,
    const float* __restrict__ aabb, const float* __restrict__ featsT,
    const float* __restrict__ w1, const float* __restrict__ b1,
    const float* __restrict__ w2, const float* __restrict__ b2,
    const float* __restrict__ w3, const float* __restrict__ b3,
    const float* __restrict__ wa, const float* __restrict__ ba,
    const float* __restrict__ wc, const float* __restrict__ bc,
    float* __restrict__ new_xyz, float* __restrict__ out_feat,
    float* __restrict__ scores, unsigned* __restrict__ prog) {
  __shared__ __align__(16) char smem[16 * 8832];   // 141312 B
  const int blk = blockIdx.x;
  const int t = threadIdx.x;
  const int lane = t & 63;
  const int w = t >> 6;

  if (blk < 2) {
    // ======================= FPS path (R13) =======================
    const int bb = blk;
    const int grp = lane >> 3;
    const int sub8 = lane & 7;
    const int s0 = (w << 6) | lane;
    const float* P = xyz + (size_t)bb * kN * 3;
    const f32x2* XP = (const f32x2*)(pxx + (size_t)bb * kN);
    const f32x2* YP = (const f32x2*)(pxy + (size_t)bb * kN);
    const f32x2* ZP = (const f32x2*)(pxz + (size_t)bb * kN);
    const uint2* OP = (const uint2*)(pxo + (size_t)bb * kN);

    float4* CW = (float4*)smem;                          // 16 KB
    f32x2* dpair = (f32x2*)(smem + 16384);               // 64 KB
    uint2* M2 = (uint2*)(smem + 81920);                  // 8 KB
    unsigned* list_ = (unsigned*)(smem + 90112);         // [16][64]
    unsigned* whi = (unsigned*)(smem + 94208);           // [2][16]
    unsigned* wlo = whi + 32;

    for (int i = t; i < kNP; i += 1024) dpair[i] = f32x2{1e10f, 1e10f};
    if (t < kNC16) M2[t] = uint2{__float_as_uint(1e10f), 0u};

    const int c0 = (lane << 4) | w;
    const float* AB = aabb + (size_t)bb * 6 * kNC16;
    float ux = AB[c0], uy = AB[kNC16 + c0], uz = AB[2 * kNC16 + c0];
    float hx = AB[3 * kNC16 + c0], hy = AB[4 * kNC16 + c0], hz = AB[5 * kNC16 + c0];
    asm volatile("" : "+v"(ux), "+v"(uy), "+v"(uz), "+v"(hx), "+v"(hy), "+v"(hz));
    __syncthreads();

    float cx = P[0], cy = P[1], cz = P[2];

    for (int it = 0; it < kS; ++it) {
      if (t == 0) {
        float* o = new_xyz + ((size_t)bb * kS + it) * 3;
        o[0] = cx; o[1] = cy; o[2] = cz;
        if (((it + 1) & 31) == 0)
          __hip_atomic_store(&prog[bb], (unsigned)(it + 1),
                             __ATOMIC_RELEASE, __HIP_MEMORY_SCOPE_AGENT);
      }
      {
        float txd = fmaxf(fabsf(cx - ux) - hx, 0.0f);
        float tyd = fmaxf(fabsf(cy - uy) - hy, 0.0f);
        float tzd = fmaxf(fabsf(cz - uz) - hz, 0.0f);
        float lb2 = txd * txd + tyd * tyd + tzd * tzd;
        float Mv = __uint_as_float(M2[s0].x);
        bool fail = !(lb2 >= Mv * 1.00001f + 1e-5f);
        unsigned long long fmask = __ballot(fail);
        int nf = (int)__popcll(fmask);
        if (fail) {
          int pos = (int)__popcll(fmask & ((1ull << lane) - 1ull));
          list_[w * 64 + pos] = (unsigned)lane;
        }
        const f32x2 ncx = f32x2{-cx, -cx};
        const f32x2 ncy = f32x2{-cy, -cy};
        const f32x2 ncz = f32x2{-cz, -cz};
        const int npass = (nf + 7) >> 3;
        for (int i = 0; i < npass; ++i) {
          int idx = min(i * 8 + grp, nf - 1);
          int cl = (int)list_[w * 64 + idx];
          int pb = (((cl << 4) | w) << 3) | sub8;
          f32x2 xp = XP[pb], yp = YP[pb], zp = ZP[pb];
          uint2 op = OP[pb];
          f32x2 dold = dpair[pb];
          f32x2 dx_, dy_, dz_, xx_, yy_, zz_, s1_, d2_;
          PK_ADD(dx_, xp, ncx);
          PK_ADD(dy_, yp, ncy);
          PK_ADD(dz_, zp, ncz);
          PK_MUL(xx_, dx_, dx_);
          PK_MUL(yy_, dy_, dy_);
          PK_MUL(zz_, dz_, dz_);
          PK_ADD(s1_, xx_, yy_);
          PK_ADD(d2_, s1_, zz_);
          f32x2 dk;
          dk.x = fminf(dold.x, d2_.x);
          dk.y = fminf(dold.y, d2_.y);
          dpair[pb] = dk;
          unsigned fa = __float_as_uint(dk.x), fbv = __float_as_uint(dk.y);
          unsigned mx = max8(max(fa, fbv));
          unsigned sa = (fa == mx) ? op.x : 0u;
          unsigned sb = (fbv == mx) ? op.y : 0u;
          unsigned m2v = max8(max(sa, sb));
          const int sl = (w << 6) | cl;
          if (sub8 == 0) M2[sl] = uint2{mx, (m2v << 10) | (unsigned)sl};
          if (op.x == m2v) CW[sl] = float4{xp.x, yp.x, zp.x, 0.0f};
          if (op.y == m2v) CW[sl] = float4{xp.y, yp.y, zp.y, 0.0f};
        }
      }
      {
        uint2 m = M2[s0];
        unsigned hi = m.x, lo = m.y;
        u64max_dpp<0xB1>(hi, lo);
        u64max_dpp<0x4E>(hi, lo);
        u64max_dpp<0x124>(hi, lo);
        u64max_dpp<0x128>(hi, lo);
        u64max_dpp<0x142>(hi, lo);
        u64max_dpp<0x143>(hi, lo);
        if (lane == 63) { whi[(it & 1) * 16 + w] = hi; wlo[(it & 1) * 16 + w] = lo; }
      }
      __syncthreads();
      {
        unsigned hi = whi[(it & 1) * 16 + (lane & 15)];
        unsigned lo = wlo[(it & 1) * 16 + (lane & 15)];
        u64max_dpp<0x121>(hi, lo);
        u64max_dpp<0x122>(hi, lo);
        u64max_dpp<0x124>(hi, lo);
        u64max_dpp<0x128>(hi, lo);
        float4 cw = CW[lo & 1023u];
        cx = cw.x; cy = cw.y; cz = cw.z;
      }
    }
    if (t == 0)
      __hip_atomic_store(&prog[bb], (unsigned)kS,
                         __ATOMIC_RELEASE, __HIP_MEMORY_SCOPE_AGENT);
  } else {
    // ======================= consumer path =======================
    float* Xs = (float*)(smem + (size_t)w * 8832);   // [32][68]
    int* idxs = (int*)(Xs + 32 * 68);                // [32]
    const int v = (blk - 2) * 16 + w;                // 0..4063
    for (int g = v; g < kB * kS; g += 4064) {
      const int b = g >> 12;
      const int q = g & (kS - 1);
      // spin until fps has published this query (bounded: bug -> absmax fail)
      const unsigned tgt = (unsigned)q + 1u;
      int guard = 0;
      while (__hip_atomic_load(&prog[b], __ATOMIC_ACQUIRE,
                               __HIP_MEMORY_SCOPE_AGENT) < tgt &&
             guard < (1 << 21)) {
        __builtin_amdgcn_s_sleep(32);
        ++guard;
      }
      const float* nxp = new_xyz + ((size_t)b * kS + q) * 3;
      const float qx = __hip_atomic_load(nxp + 0, __ATOMIC_RELAXED, __HIP_MEMORY_SCOPE_AGENT);
      const float qy = __hip_atomic_load(nxp + 1, __ATOMIC_RELAXED, __HIP_MEMORY_SCOPE_AGENT);
      const float qz = __hip_atomic_load(nxp + 2, __ATOMIC_RELAXED, __HIP_MEMORY_SCOPE_AGENT);
      const float* Pb = xyz + (size_t)b * kN * 3;
      const float* F = featsT + (size_t)b * kN * kC;
      // ---- ball query (identical math/semantics to R13 kernel) ----
      {
        int cnt = 0;
        int first = -1;
        for (int j = 0; j < kN / 64; j++) {
          const int p = (j << 6) + lane;
          float dx = Pb[p * 3 + 0] - qx;
          float dy = Pb[p * 3 + 1] - qy;
          float dz = Pb[p * 3 + 2] - qz;
          float d = __fadd_rn(__fadd_rn(__fmul_rn(dx, dx), __fmul_rn(dy, dy)),
                              __fmul_rn(dz, dz));
          bool inb = d < 0.25f;
          unsigned long long m = __ballot(inb);
          if (first < 0 && m != 0ull) first = (j << 6) + (__ffsll(m) - 1);
          if (inb && cnt < kNS) {
            int r = cnt + (int)__popcll(m & ((1ull << lane) - 1ull));
            if (r < kNS) idxs[r] = p;
          }
          cnt += (int)__popcll(m);
          if (cnt >= kNS) break;
        }
        if (cnt < kNS) {
          int fill = (first >= 0) ? first : 0;
          if (lane >= cnt && lane < kNS) idxs[lane] = fill;
        }
      }
      // ---- gather (group_mlp-identical values) ----
      if (lane < 32) {
        int p = idxs[lane];
        Xs[lane * 68 + 0] = Pb[p * 3 + 0] - qx;
        Xs[lane * 68 + 1] = Pb[p * 3 + 1] - qy;
        Xs[lane * 68 + 2] = Pb[p * 3 + 2] - qz;
      } else {
        Xs[(lane - 32) * 68 + 67] = 0.0f;   // pad column
      }
      for (int j = 0; j < 32; j++)
        Xs[j * 68 + 3 + lane] = F[(size_t)idxs[j] * kC + lane];
      // ---- layer 1: 67 -> 64, in-place (row r out overwrites row r in) ----
      {
        float wv[68];
#pragma unroll
        for (int k = 0; k < 67; k++) wv[k] = w1[lane * 67 + k];
        wv[67] = 0.0f;
        const float bias = b1[lane];
        for (int r = 0; r < 32; r++) {
          float acc = bias;
#pragma unroll
          for (int k4 = 0; k4 < 17; k4++) {
            float4 x = *(const float4*)&Xs[r * 68 + k4 * 4];
            acc += x.x * wv[k4 * 4 + 0] + x.y * wv[k4 * 4 + 1] +
                   x.z * wv[k4 * 4 + 2] + x.w * wv[k4 * 4 + 3];
          }
          Xs[r * 68 + lane] = fmaxf(acc, 0.0f);
        }
      }
      // ---- layer 2: 64 -> 64, in-place ----
      {
        float wv[64];
#pragma unroll
        for (int k = 0; k < 64; k++) wv[k] = w2[lane * 64 + k];
        const float bias = b2[lane];
        for (int r = 0; r < 32; r++) {
          float acc = bias;
#pragma unroll
          for (int k4 = 0; k4 < 16; k4++) {
            float4 x = *(const float4*)&Xs[r * 68 + k4 * 4];
            acc += x.x * wv[k4 * 4 + 0] + x.y * wv[k4 * 4 + 1] +
                   x.z * wv[k4 * 4 + 2] + x.w * wv[k4 * 4 + 3];
          }
          Xs[r * 68 + lane] = fmaxf(acc, 0.0f);
        }
      }
      // ---- layer 3: 64 -> 128 in two halves + maxpool (relu folded) ----
      float pph[2];
#pragma unroll
      for (int h = 0; h < 2; h++) {
        float wv[64];
#pragma unroll
        for (int k = 0; k < 64; k++) wv[k] = w3[(lane + 64 * h) * 64 + k];
        const float bias = b3[lane + 64 * h];
        float pm = 0.0f;
        for (int r = 0; r < 32; r++) {
          float acc = bias;
#pragma unroll
          for (int k4 = 0; k4 < 16; k4++) {
            float4 x = *(const float4*)&Xs[r * 68 + k4 * 4];
            acc += x.x * wv[k4 * 4 + 0] + x.y * wv[k4 * 4 + 1] +
                   x.z * wv[k4 * 4 + 2] + x.w * wv[k4 * 4 + 3];
          }
          pm = fmaxf(pm, acc);
        }
        pph[h] = pm;
      }
      Xs[lane] = pph[0];
      Xs[64 + lane] = pph[1];
      // ---- aggregation 128->128 + relu, direct out_feat + score ----
      {
        float accA = ba[lane], accB = ba[lane + 64];
#pragma unroll
        for (int k4 = 0; k4 < 32; k4++) {
          float4 pv = *(const float4*)&Xs[k4 * 4];
          float4 wva = *(const float4*)&wa[lane * 128 + k4 * 4];
          float4 wvb = *(const float4*)&wa[(lane + 64) * 128 + k4 * 4];
          accA += pv.x * wva.x + pv.y * wva.y + pv.z * wva.z + pv.w * wva.w;
          accB += pv.x * wvb.x + pv.y * wvb.y + pv.z * wvb.z + pv.w * wvb.w;
        }
        float aggA = fmaxf(accA, 0.0f);
        float aggB = fmaxf(accB, 0.0f);
        out_feat[((size_t)b * 128 + lane) * kS + q] = aggA;
        out_feat[((size_t)b * 128 + 64 + lane) * kS + q] = aggB;
        float partial = aggA * wc[lane] + aggB * wc[lane + 64];
#pragma unroll
        for (int off = 32; off >= 1; off >>= 1)
          partial += __shfl_xor(partial, off, 64);
        if (lane == 0) scores[(size_t)b * kS + q] = partial + bc[0];
      }
    }
  }
}

extern "C" void kernel_launch(void* const* d_in, const int* in_sizes, int n_in,
                              void* d_out, int out_size, void* d_ws, size_t ws_size,
                              hipStream_t stream) {
  const float* xyz   = (const float*)d_in[0];
  const float* feats = (const float*)d_in[1];
  const float* w1 = (const float*)d_in[2];
  const float* b1 = (const float*)d_in[3];
  const float* w2 = (const float*)d_in[4];
  const float* b2 = (const float*)d_in[5];
  const float* w3 = (const float*)d_in[6];
  const float* b3 = (const float*)d_in[7];
  const float* wa = (const float*)d_in[8];
  const float* ba = (const float*)d_in[9];
  const float* wc = (const float*)d_in[10];
  const float* bc = (const float*)d_in[11];

  float* out_new_xyz = (float*)d_out;                               // B*S*3
  float* out_feat    = out_new_xyz + (size_t)kB * kS * 3;           // B*128*S
  float* out_scores  = out_feat + (size_t)kB * 128 * kS;            // B*S

  // ws layout: featsT [0,8MiB); prep buffers at [9MiB, ...):
  // pxx/pxy/pxz/pxo 4x128KB, aabb 48KB, prog 64B @ +576KB.
  char* ws = (char*)d_ws;
  float* featsT = (float*)ws;
  float*    pxx = (float*)(ws + (size_t)9 * 1024 * 1024);
  float*    pxy = (float*)(ws + (size_t)9 * 1024 * 1024 + 128 * 1024);
  float*    pxz = (float*)(ws + (size_t)9 * 1024 * 1024 + 256 * 1024);
  unsigned* pxo = (unsigned*)(ws + (size_t)9 * 1024 * 1024 + 384 * 1024);
  float*   aabb = (float*)(ws + (size_t)9 * 1024 * 1024 + 512 * 1024);
  unsigned* prog = (unsigned*)(ws + (size_t)9 * 1024 * 1024 + 576 * 1024);

  // features (B,C,N) -> featsT (B,N,C)
  transpose_kernel<<<dim3(kN / 32, kC / 32, kB), dim3(32, 8, 1), 0, stream>>>(
      feats, featsT, kC, kN);
  // FPS prep (also zeroes progress counters for this invocation)
  fps_prep_kernel<<<dim3(kB), dim3(1024), 0, stream>>>(
      xyz, pxx, pxy, pxz, pxo, aabb, prog);
  // fused FPS + ball query + MLP: 256 blocks = 1/CU, all co-resident
  fused_kernel<<<dim3(256), dim3(1024), 0, stream>>>(
      xyz, pxx, pxy, pxz, pxo, aabb, featsT,
      w1, b1, w2, b2, w3, b3, wa, ba, wc, bc,
      out_new_xyz, out_feat, out_scores, prog);
}

// Round 16
// 7546.151 us; speedup vs baseline: 1.5258x; 1.5258x over previous
//
#include <hip/hip_runtime.h>
#include <cstddef>

constexpr int kB = 2;
constexpr int kN = 16384;
constexpr int kC = 64;
constexpr int kS = 4096;    // NPOINT
constexpr int kNS = 32;     // NSAMPLE
constexpr int kNC16 = 1024; // 16-point chunks per batch
constexpr int kNP = kN / 2; // point pairs per batch

typedef float f32x2 __attribute__((ext_vector_type(2)));

__device__ __forceinline__ unsigned expand10(unsigned v) {
  v &= 1023u;
  v = (v | (v << 16)) & 0x030000FFu;
  v = (v | (v <<  8)) & 0x0300F00Fu;
  v = (v | (v <<  4)) & 0x030C30C3u;
  v = (v | (v <<  2)) & 0x09249249u;
  return v;
}

template <int C>
__device__ __forceinline__ unsigned dpp_u32(unsigned x) {
  return (unsigned)__builtin_amdgcn_update_dpp((int)x, (int)x, C, 0xF, 0xF, false);
}
__device__ __forceinline__ unsigned max8(unsigned x) {
  x = max(x, dpp_u32<0xB1>(x));   // quad_perm [1,0,3,2]
  x = max(x, dpp_u32<0x4E>(x));   // quad_perm [2,3,0,1]
  x = max(x, dpp_u32<0x141>(x));  // row_half_mirror
  return x;
}
template <int C>
__device__ __forceinline__ void u64max_dpp(unsigned& hi, unsigned& lo) {
  unsigned h2 = dpp_u32<C>(hi), l2 = dpp_u32<C>(lo);
  bool g = (h2 > hi) || (h2 == hi && l2 > lo);
  hi = g ? h2 : hi;
  lo = g ? l2 : lo;
}

#define PK_ADD(d, a, b) asm("v_pk_add_f32 %0, %1, %2" : "=v"(d) : "v"(a), "v"(b))
#define PK_MUL(d, a, b) asm("v_pk_mul_f32 %0, %1, %2" : "=v"(d) : "v"(a), "v"(b))

// -------- transpose [b][Cdim][Ndim] -> [b][Ndim][Cdim], 32x32 tiles --------
__global__ void transpose_kernel(const float* __restrict__ in,
                                 float* __restrict__ out,
                                 int Cdim, int Ndim) {
  __shared__ float tile[32][33];
  int b = blockIdx.z;
  int n0 = blockIdx.x * 32;
  int c0 = blockIdx.y * 32;
  int tx = threadIdx.x;
  const float* inb = in + (size_t)b * Cdim * Ndim;
  float* outb = out + (size_t)b * Cdim * Ndim;
#pragma unroll
  for (int i = threadIdx.y; i < 32; i += 8)
    tile[i][tx] = inb[(size_t)(c0 + i) * Ndim + (n0 + tx)];
  __syncthreads();
#pragma unroll
  for (int i = threadIdx.y; i < 32; i += 8)
    outb[(size_t)(n0 + i) * Cdim + (c0 + tx)] = tile[tx][i];
}

// -------- FPS prep (unchanged R9-R13) + progress zeroing --------
__global__ __launch_bounds__(1024) void fps_prep_kernel(
    const float* __restrict__ xyz, float* __restrict__ pxx,
    float* __restrict__ pxy, float* __restrict__ pxz,
    unsigned* __restrict__ pxo, float* __restrict__ aabb,
    unsigned* __restrict__ prog) {
  const int b = blockIdx.x;
  const int t = threadIdx.x;
  const int lane = t & 63;
  const int w = t >> 6;
  if (t == 0)
    __hip_atomic_store(&prog[b], 0u, __ATOMIC_RELEASE, __HIP_MEMORY_SCOPE_AGENT);
  const float* P = xyz + (size_t)b * kN * 3;
  __shared__ unsigned long long keys[kN];   // 128 KB
  __shared__ float sbb[6][16];

  float mnx = 3e38f, mny = 3e38f, mnz = 3e38f;
  float mxx = -3e38f, mxy = -3e38f, mxz = -3e38f;
  for (int p = t; p < kN; p += 1024) {
    float x = P[p * 3], y = P[p * 3 + 1], z = P[p * 3 + 2];
    mnx = fminf(mnx, x); mny = fminf(mny, y); mnz = fminf(mnz, z);
    mxx = fmaxf(mxx, x); mxy = fmaxf(mxy, y); mxz = fmaxf(mxz, z);
  }
#pragma unroll
  for (int off = 32; off >= 1; off >>= 1) {
    mnx = fminf(mnx, __shfl_xor(mnx, off, 64));
    mny = fminf(mny, __shfl_xor(mny, off, 64));
    mnz = fminf(mnz, __shfl_xor(mnz, off, 64));
    mxx = fmaxf(mxx, __shfl_xor(mxx, off, 64));
    mxy = fmaxf(mxy, __shfl_xor(mxy, off, 64));
    mxz = fmaxf(mxz, __shfl_xor(mxz, off, 64));
  }
  if (lane == 0) {
    sbb[0][w] = mnx; sbb[1][w] = mny; sbb[2][w] = mnz;
    sbb[3][w] = mxx; sbb[4][w] = mxy; sbb[5][w] = mxz;
  }
  __syncthreads();
  mnx = sbb[0][lane & 15]; mny = sbb[1][lane & 15]; mnz = sbb[2][lane & 15];
  mxx = sbb[3][lane & 15]; mxy = sbb[4][lane & 15]; mxz = sbb[5][lane & 15];
#pragma unroll
  for (int off = 8; off >= 1; off >>= 1) {
    mnx = fminf(mnx, __shfl_xor(mnx, off, 64));
    mny = fminf(mny, __shfl_xor(mny, off, 64));
    mnz = fminf(mnz, __shfl_xor(mnz, off, 64));
    mxx = fmaxf(mxx, __shfl_xor(mxx, off, 64));
    mxy = fmaxf(mxy, __shfl_xor(mxy, off, 64));
    mxz = fmaxf(mxz, __shfl_xor(mxz, off, 64));
  }
  __syncthreads();
  const float sx = 1023.0f / fmaxf(mxx - mnx, 1e-20f);
  const float sy = 1023.0f / fmaxf(mxy - mny, 1e-20f);
  const float sz = 1023.0f / fmaxf(mxz - mnz, 1e-20f);
  for (int p = t; p < kN; p += 1024) {
    float x = P[p * 3], y = P[p * 3 + 1], z = P[p * 3 + 2];
    int qx = (int)((x - mnx) * sx); qx = max(0, min(1023, qx));
    int qy = (int)((y - mny) * sy); qy = max(0, min(1023, qy));
    int qz = (int)((z - mnz) * sz); qz = max(0, min(1023, qz));
    unsigned mort = (expand10((unsigned)qx) << 2) |
                    (expand10((unsigned)qy) << 1) | expand10((unsigned)qz);
    keys[p] = ((unsigned long long)mort << 14) | (unsigned)p;
  }
  __syncthreads();
  for (unsigned k = 2; k <= (unsigned)kN; k <<= 1) {
    for (unsigned j = k >> 1; j > 0; j >>= 1) {
      for (int i = t; i < kN; i += 1024) {
        int l = i ^ (int)j;
        if (l > i) {
          unsigned long long a = keys[i], c = keys[l];
          bool asc = ((i & (int)k) == 0);
          if ((a > c) == asc) { keys[i] = c; keys[l] = a; }
        }
      }
      __syncthreads();
    }
  }
  float* FX = pxx + (size_t)b * kN;
  float* FY = pxy + (size_t)b * kN;
  float* FZ = pxz + (size_t)b * kN;
  unsigned* FO = pxo + (size_t)b * kN;
  for (int i = t; i < kN; i += 1024) {
    int o = (int)(keys[i] & 0x3FFFull);
    int c = i >> 4, j = i & 15;
    int fi = c * 16 + ((j & 7) << 1) + (j >> 3);
    FX[fi] = P[o * 3];
    FY[fi] = P[o * 3 + 1];
    FZ[fi] = P[o * 3 + 2];
    FO[fi] = 16383u - (unsigned)o;   // tie key: max(16383-o) == min orig
  }
  if (t < kNC16) {
    float amn = 3e38f, bmn = 3e38f, cmn = 3e38f;
    float amx = -3e38f, bmx = -3e38f, cmx = -3e38f;
    for (int kk = 0; kk < 16; kk++) {
      int o = (int)(keys[t * 16 + kk] & 0x3FFFull);
      float x = P[o * 3], y = P[o * 3 + 1], z = P[o * 3 + 2];
      amn = fminf(amn, x); amx = fmaxf(amx, x);
      bmn = fminf(bmn, y); bmx = fmaxf(bmx, y);
      cmn = fminf(cmn, z); cmx = fmaxf(cmx, z);
    }
    float* AB = aabb + (size_t)b * 6 * kNC16;
    AB[0 * kNC16 + t] = (amn + amx) * 0.5f;
    AB[1 * kNC16 + t] = (bmn + bmx) * 0.5f;
    AB[2 * kNC16 + t] = (cmn + cmx) * 0.5f;
    AB[3 * kNC16 + t] = (amx - amn) * 0.5f * 1.0001f + 2e-7f;
    AB[4 * kNC16 + t] = (bmx - bmn) * 0.5f * 1.0001f + 2e-7f;
    AB[5 * kNC16 + t] = (cmx - cmn) * 0.5f * 1.0001f + 2e-7f;
  }
}

// -------- FUSED kernel v2: fps (blocks 0-1) + consumers (blocks 2-255) ----
// R15 lesson: per-poll ACQUIRE loads invalidate caches on every poll ->
// 828MB HBM re-fetch + 2x fps slowdown. v2 synchronization:
//  * polls are atomic RMW (atomicAdd(p,0), device-coherent per G12), lane-0
//    only, deficit-proportional s_sleep backoff -> no cache invalidation;
//  * coords flow through cbuf (float4/query; 32-query publish batch = 512B =
//    4 whole 128B lines). Consumer proceeds only when prog >= 32*(batch+1),
//    so every cbuf line is FINAL before first touch -> plain cached loads
//    are fresh; release store of prog (L2 writeback) orders the flush.
//  * waves_per_eu(4,4): VGPR budget 128 so consumer weight rows stay in regs.
// Residency: 256 blocks x 141KB LDS = 1/CU, all co-resident; bounded spin
// guard converts logic bugs into loud absmax failures, never hangs.
__global__ __attribute__((amdgpu_flat_work_group_size(1024, 1024),
                          amdgpu_waves_per_eu(4, 4)))
void fused_kernel(
    const float* __restrict__ xyz,
    const float* __restrict__ pxx, const float* __restrict__ pxy,
    const float* __restrict__ pxz, const unsigned* __restrict__ pxo,
    const float* __restrict__ aabb, const float* __restrict__ featsT,
    const float* __restrict__ w1, const float* __restrict__ b1,
    const float* __restrict__ w2, const float* __restrict__ b2,
    const float* __restrict__ w3, const float* __restrict__ b3,
    const float* __restrict__ wa, const float* __restrict__ ba,
    const float* __restrict__ wc, const float* __restrict__ bc,
    float* __restrict__ new_xyz, float4* __restrict__ cbuf,
    float* __restrict__ out_feat, float* __restrict__ scores,
    unsigned* __restrict__ prog) {
  __shared__ __align__(16) char smem[16 * 8832];   // 141312 B
  const int blk = blockIdx.x;
  const int t = threadIdx.x;
  const int lane = t & 63;
  const int w = t >> 6;

  if (blk < 2) {
    // ======================= FPS path (R13 verbatim) =======================
    const int bb = blk;
    const int grp = lane >> 3;
    const int sub8 = lane & 7;
    const int s0 = (w << 6) | lane;
    const float* P = xyz + (size_t)bb * kN * 3;
    const f32x2* XP = (const f32x2*)(pxx + (size_t)bb * kN);
    const f32x2* YP = (const f32x2*)(pxy + (size_t)bb * kN);
    const f32x2* ZP = (const f32x2*)(pxz + (size_t)bb * kN);
    const uint2* OP = (const uint2*)(pxo + (size_t)bb * kN);

    float4* CW = (float4*)smem;                          // 16 KB
    f32x2* dpair = (f32x2*)(smem + 16384);               // 64 KB
    uint2* M2 = (uint2*)(smem + 81920);                  // 8 KB
    unsigned* list_ = (unsigned*)(smem + 90112);         // [16][64]
    unsigned* whi = (unsigned*)(smem + 94208);           // [2][16]
    unsigned* wlo = whi + 32;

    for (int i = t; i < kNP; i += 1024) dpair[i] = f32x2{1e10f, 1e10f};
    if (t < kNC16) M2[t] = uint2{__float_as_uint(1e10f), 0u};

    const int c0 = (lane << 4) | w;
    const float* AB = aabb + (size_t)bb * 6 * kNC16;
    float ux = AB[c0], uy = AB[kNC16 + c0], uz = AB[2 * kNC16 + c0];
    float hx = AB[3 * kNC16 + c0], hy = AB[4 * kNC16 + c0], hz = AB[5 * kNC16 + c0];
    asm volatile("" : "+v"(ux), "+v"(uy), "+v"(uz), "+v"(hx), "+v"(hy), "+v"(hz));
    __syncthreads();

    float cx = P[0], cy = P[1], cz = P[2];

    for (int it = 0; it < kS; ++it) {
      if (t == 0) {
        float* o = new_xyz + ((size_t)bb * kS + it) * 3;
        o[0] = cx; o[1] = cy; o[2] = cz;
        cbuf[((size_t)bb << 12) | it] = float4{cx, cy, cz, 0.0f};
        if (((it + 1) & 31) == 0)
          __hip_atomic_store(&prog[bb], (unsigned)(it + 1),
                             __ATOMIC_RELEASE, __HIP_MEMORY_SCOPE_AGENT);
      }
      {
        float txd = fmaxf(fabsf(cx - ux) - hx, 0.0f);
        float tyd = fmaxf(fabsf(cy - uy) - hy, 0.0f);
        float tzd = fmaxf(fabsf(cz - uz) - hz, 0.0f);
        float lb2 = txd * txd + tyd * tyd + tzd * tzd;
        float Mv = __uint_as_float(M2[s0].x);
        bool fail = !(lb2 >= Mv * 1.00001f + 1e-5f);
        unsigned long long fmask = __ballot(fail);
        int nf = (int)__popcll(fmask);
        if (fail) {
          int pos = (int)__popcll(fmask & ((1ull << lane) - 1ull));
          list_[w * 64 + pos] = (unsigned)lane;
        }
        const f32x2 ncx = f32x2{-cx, -cx};
        const f32x2 ncy = f32x2{-cy, -cy};
        const f32x2 ncz = f32x2{-cz, -cz};
        const int npass = (nf + 7) >> 3;
        for (int i = 0; i < npass; ++i) {
          int idx = min(i * 8 + grp, nf - 1);
          int cl = (int)list_[w * 64 + idx];
          int pb = (((cl << 4) | w) << 3) | sub8;
          f32x2 xp = XP[pb], yp = YP[pb], zp = ZP[pb];
          uint2 op = OP[pb];
          f32x2 dold = dpair[pb];
          f32x2 dx_, dy_, dz_, xx_, yy_, zz_, s1_, d2_;
          PK_ADD(dx_, xp, ncx);
          PK_ADD(dy_, yp, ncy);
          PK_ADD(dz_, zp, ncz);
          PK_MUL(xx_, dx_, dx_);
          PK_MUL(yy_, dy_, dy_);
          PK_MUL(zz_, dz_, dz_);
          PK_ADD(s1_, xx_, yy_);
          PK_ADD(d2_, s1_, zz_);
          f32x2 dk;
          dk.x = fminf(dold.x, d2_.x);
          dk.y = fminf(dold.y, d2_.y);
          dpair[pb] = dk;
          unsigned fa = __float_as_uint(dk.x), fbv = __float_as_uint(dk.y);
          unsigned mx = max8(max(fa, fbv));
          unsigned sa = (fa == mx) ? op.x : 0u;
          unsigned sb = (fbv == mx) ? op.y : 0u;
          unsigned m2v = max8(max(sa, sb));
          const int sl = (w << 6) | cl;
          if (sub8 == 0) M2[sl] = uint2{mx, (m2v << 10) | (unsigned)sl};
          if (op.x == m2v) CW[sl] = float4{xp.x, yp.x, zp.x, 0.0f};
          if (op.y == m2v) CW[sl] = float4{xp.y, yp.y, zp.y, 0.0f};
        }
      }
      {
        uint2 m = M2[s0];
        unsigned hi = m.x, lo = m.y;
        u64max_dpp<0xB1>(hi, lo);
        u64max_dpp<0x4E>(hi, lo);
        u64max_dpp<0x124>(hi, lo);
        u64max_dpp<0x128>(hi, lo);
        u64max_dpp<0x142>(hi, lo);
        u64max_dpp<0x143>(hi, lo);
        if (lane == 63) { whi[(it & 1) * 16 + w] = hi; wlo[(it & 1) * 16 + w] = lo; }
      }
      __syncthreads();
      {
        unsigned hi = whi[(it & 1) * 16 + (lane & 15)];
        unsigned lo = wlo[(it & 1) * 16 + (lane & 15)];
        u64max_dpp<0x121>(hi, lo);
        u64max_dpp<0x122>(hi, lo);
        u64max_dpp<0x124>(hi, lo);
        u64max_dpp<0x128>(hi, lo);
        float4 cw = CW[lo & 1023u];
        cx = cw.x; cy = cw.y; cz = cw.z;
      }
    }
    if (t == 0)
      __hip_atomic_store(&prog[bb], (unsigned)kS,
                         __ATOMIC_RELEASE, __HIP_MEMORY_SCOPE_AGENT);
  } else {
    // ======================= consumer path =======================
    float* Xs = (float*)(smem + (size_t)w * 8832);   // [32][68]
    int* idxs = (int*)(Xs + 32 * 68);                // [32]
    const int v = (blk - 2) * 16 + w;                // 0..4063
    for (int g = v; g < kB * kS; g += 4064) {
      const int b = g >> 12;
      const int q = g & (kS - 1);
      const unsigned tgt = (unsigned)q + 1u;
      // poll: lane-0 atomic RMW (coherent, no cache inval), backoff sleep
      unsigned cur = 0;
      if (lane == 0) cur = atomicAdd(&prog[b], 0u);
      cur = (unsigned)__shfl((int)cur, 0, 64);
      int guard = 0;
      while (cur < tgt && guard < (1 << 15)) {
        int def = (int)(tgt - cur);
        int reps = min(def >> 5, 7) + 1;
        for (int r = 0; r < reps; ++r) __builtin_amdgcn_s_sleep(127);
        if (lane == 0) cur = atomicAdd(&prog[b], 0u);
        cur = (unsigned)__shfl((int)cur, 0, 64);
        ++guard;
      }
      const float4 cw = cbuf[((size_t)b << 12) | q];   // line final pre-touch
      const float qx = cw.x, qy = cw.y, qz = cw.z;
      const float* Pb = xyz + (size_t)b * kN * 3;
      const float* F = featsT + (size_t)b * kN * kC;
      // ---- ball query (identical math/semantics to R13 kernel) ----
      {
        int cnt = 0;
        int first = -1;
        for (int j = 0; j < kN / 64; j++) {
          const int p = (j << 6) + lane;
          float dx = Pb[p * 3 + 0] - qx;
          float dy = Pb[p * 3 + 1] - qy;
          float dz = Pb[p * 3 + 2] - qz;
          float d = __fadd_rn(__fadd_rn(__fmul_rn(dx, dx), __fmul_rn(dy, dy)),
                              __fmul_rn(dz, dz));
          bool inb = d < 0.25f;
          unsigned long long m = __ballot(inb);
          if (first < 0 && m != 0ull) first = (j << 6) + (__ffsll(m) - 1);
          if (inb && cnt < kNS) {
            int r = cnt + (int)__popcll(m & ((1ull << lane) - 1ull));
            if (r < kNS) idxs[r] = p;
          }
          cnt += (int)__popcll(m);
          if (cnt >= kNS) break;
        }
        if (cnt < kNS) {
          int fill = (first >= 0) ? first : 0;
          if (lane >= cnt && lane < kNS) idxs[lane] = fill;
        }
      }
      // ---- gather (group_mlp-identical values) ----
      if (lane < 32) {
        int p = idxs[lane];
        Xs[lane * 68 + 0] = Pb[p * 3 + 0] - qx;
        Xs[lane * 68 + 1] = Pb[p * 3 + 1] - qy;
        Xs[lane * 68 + 2] = Pb[p * 3 + 2] - qz;
      } else {
        Xs[(lane - 32) * 68 + 67] = 0.0f;   // pad column
      }
      for (int j = 0; j < 32; j++)
        Xs[j * 68 + 3 + lane] = F[(size_t)idxs[j] * kC + lane];
      // ---- layer 1: 67 -> 64, in-place ----
      {
        float wv[68];
#pragma unroll
        for (int k = 0; k < 67; k++) wv[k] = w1[lane * 67 + k];
        wv[67] = 0.0f;
        const float bias = b1[lane];
        for (int r = 0; r < 32; r++) {
          float acc = bias;
#pragma unroll
          for (int k4 = 0; k4 < 17; k4++) {
            float4 x = *(const float4*)&Xs[r * 68 + k4 * 4];
            acc += x.x * wv[k4 * 4 + 0] + x.y * wv[k4 * 4 + 1] +
                   x.z * wv[k4 * 4 + 2] + x.w * wv[k4 * 4 + 3];
          }
          Xs[r * 68 + lane] = fmaxf(acc, 0.0f);
        }
      }
      // ---- layer 2: 64 -> 64, in-place ----
      {
        float wv[64];
#pragma unroll
        for (int k = 0; k < 64; k++) wv[k] = w2[lane * 64 + k];
        const float bias = b2[lane];
        for (int r = 0; r < 32; r++) {
          float acc = bias;
#pragma unroll
          for (int k4 = 0; k4 < 16; k4++) {
            float4 x = *(const float4*)&Xs[r * 68 + k4 * 4];
            acc += x.x * wv[k4 * 4 + 0] + x.y * wv[k4 * 4 + 1] +
                   x.z * wv[k4 * 4 + 2] + x.w * wv[k4 * 4 + 3];
          }
          Xs[r * 68 + lane] = fmaxf(acc, 0.0f);
        }
      }
      // ---- layer 3: 64 -> 128 in two halves + maxpool (relu folded) ----
      float pph[2];
#pragma unroll
      for (int h = 0; h < 2; h++) {
        float wv[64];
#pragma unroll
        for (int k = 0; k < 64; k++) wv[k] = w3[(lane + 64 * h) * 64 + k];
        const float bias = b3[lane + 64 * h];
        float pm = 0.0f;
        for (int r = 0; r < 32; r++) {
          float acc = bias;
#pragma unroll
          for (int k4 = 0; k4 < 16; k4++) {
            float4 x = *(const float4*)&Xs[r * 68 + k4 * 4];
            acc += x.x * wv[k4 * 4 + 0] + x.y * wv[k4 * 4 + 1] +
                   x.z * wv[k4 * 4 + 2] + x.w * wv[k4 * 4 + 3];
          }
          pm = fmaxf(pm, acc);
        }
        pph[h] = pm;
      }
      Xs[lane] = pph[0];
      Xs[64 + lane] = pph[1];
      // ---- aggregation 128->128 + relu, direct out_feat + score ----
      {
        float accA = ba[lane], accB = ba[lane + 64];
#pragma unroll
        for (int k4 = 0; k4 < 32; k4++) {
          float4 pv = *(const float4*)&Xs[k4 * 4];
          float4 wva = *(const float4*)&wa[lane * 128 + k4 * 4];
          float4 wvb = *(const float4*)&wa[(lane + 64) * 128 + k4 * 4];
          accA += pv.x * wva.x + pv.y * wva.y + pv.z * wva.z + pv.w * wva.w;
          accB += pv.x * wvb.x + pv.y * wvb.y + pv.z * wvb.z + pv.w * wvb.w;
        }
        float aggA = fmaxf(accA, 0.0f);
        float aggB = fmaxf(accB, 0.0f);
        out_feat[((size_t)b * 128 + lane) * kS + q] = aggA;
        out_feat[((size_t)b * 128 + 64 + lane) * kS + q] = aggB;
        float partial = aggA * wc[lane] + aggB * wc[lane + 64];
#pragma unroll
        for (int off = 32; off >= 1; off >>= 1)
          partial += __shfl_xor(partial, off, 64);
        if (lane == 0) scores[(size_t)b * kS + q] = partial + bc[0];
      }
    }
  }
}

extern "C" void kernel_launch(void* const* d_in, const int* in_sizes, int n_in,
                              void* d_out, int out_size, void* d_ws, size_t ws_size,
                              hipStream_t stream) {
  const float* xyz   = (const float*)d_in[0];
  const float* feats = (const float*)d_in[1];
  const float* w1 = (const float*)d_in[2];
  const float* b1 = (const float*)d_in[3];
  const float* w2 = (const float*)d_in[4];
  const float* b2 = (const float*)d_in[5];
  const float* w3 = (const float*)d_in[6];
  const float* b3 = (const float*)d_in[7];
  const float* wa = (const float*)d_in[8];
  const float* ba = (const float*)d_in[9];
  const float* wc = (const float*)d_in[10];
  const float* bc = (const float*)d_in[11];

  float* out_new_xyz = (float*)d_out;                               // B*S*3
  float* out_feat    = out_new_xyz + (size_t)kB * kS * 3;           // B*128*S
  float* out_scores  = out_feat + (size_t)kB * 128 * kS;            // B*S

  // ws layout: featsT [0,8MiB); prep buffers at [9MiB,...):
  // pxx/pxy/pxz/pxo 4x128KB, aabb 48KB, prog 64B @+576KB, cbuf 128KB @+640KB.
  char* ws = (char*)d_ws;
  float* featsT = (float*)ws;
  float*    pxx = (float*)(ws + (size_t)9 * 1024 * 1024);
  float*    pxy = (float*)(ws + (size_t)9 * 1024 * 1024 + 128 * 1024);
  float*    pxz = (float*)(ws + (size_t)9 * 1024 * 1024 + 256 * 1024);
  unsigned* pxo = (unsigned*)(ws + (size_t)9 * 1024 * 1024 + 384 * 1024);
  float*   aabb = (float*)(ws + (size_t)9 * 1024 * 1024 + 512 * 1024);
  unsigned* prog = (unsigned*)(ws + (size_t)9 * 1024 * 1024 + 576 * 1024);
  float4*  cbuf = (float4*)(ws + (size_t)9 * 1024 * 1024 + 640 * 1024);

  // features (B,C,N) -> featsT (B,N,C)
  transpose_kernel<<<dim3(kN / 32, kC / 32, kB), dim3(32, 8, 1), 0, stream>>>(
      feats, featsT, kC, kN);
  // FPS prep (also zeroes progress counters for this invocation)
  fps_prep_kernel<<<dim3(kB), dim3(1024), 0, stream>>>(
      xyz, pxx, pxy, pxz, pxo, aabb, prog);
  // fused FPS + ball query + MLP: 256 blocks = 1/CU, all co-resident
  fused_kernel<<<dim3(256), dim3(1024), 0, stream>>>(
      xyz, pxx, pxy, pxz, pxo, aabb, featsT,
      w1, b1, w2, b2, w3, b3, wa, ba, wc, bc,
      out_new_xyz, cbuf, out_feat, out_scores, prog);
}

// Round 17
// 6072.514 us; speedup vs baseline: 1.8960x; 1.2427x over previous
//
#include <hip/hip_runtime.h>
#include <cstddef>

constexpr int kB = 2;
constexpr int kN = 16384;
constexpr int kC = 64;
constexpr int kS = 4096;    // NPOINT
constexpr int kNS = 32;     // NSAMPLE
constexpr int kNC16 = 1024; // 16-point chunks per batch
constexpr int kNP = kN / 2; // point pairs per batch

typedef float f32x2 __attribute__((ext_vector_type(2)));

__device__ __forceinline__ unsigned expand10(unsigned v) {
  v &= 1023u;
  v = (v | (v << 16)) & 0x030000FFu;
  v = (v | (v <<  8)) & 0x0300F00Fu;
  v = (v | (v <<  4)) & 0x030C30C3u;
  v = (v | (v <<  2)) & 0x09249249u;
  return v;
}

template <int C>
__device__ __forceinline__ unsigned dpp_u32(unsigned x) {
  return (unsigned)__builtin_amdgcn_update_dpp((int)x, (int)x, C, 0xF, 0xF, false);
}
__device__ __forceinline__ unsigned max8(unsigned x) {
  x = max(x, dpp_u32<0xB1>(x));   // quad_perm [1,0,3,2]
  x = max(x, dpp_u32<0x4E>(x));   // quad_perm [2,3,0,1]
  x = max(x, dpp_u32<0x141>(x));  // row_half_mirror
  return x;
}
template <int C>
__device__ __forceinline__ void u64max_dpp(unsigned& hi, unsigned& lo) {
  unsigned h2 = dpp_u32<C>(hi), l2 = dpp_u32<C>(lo);
  bool g = (h2 > hi) || (h2 == hi && l2 > lo);
  hi = g ? h2 : hi;
  lo = g ? l2 : lo;
}

#define PK_ADD(d, a, b) asm("v_pk_add_f32 %0, %1, %2" : "=v"(d) : "v"(a), "v"(b))
#define PK_MUL(d, a, b) asm("v_pk_mul_f32 %0, %1, %2" : "=v"(d) : "v"(a), "v"(b))

// -------- transpose [b][Cdim][Ndim] -> [b][Ndim][Cdim], 32x32 tiles --------
__global__ void transpose_kernel(const float* __restrict__ in,
                                 float* __restrict__ out,
                                 int Cdim, int Ndim) {
  __shared__ float tile[32][33];
  int b = blockIdx.z;
  int n0 = blockIdx.x * 32;
  int c0 = blockIdx.y * 32;
  int tx = threadIdx.x;
  const float* inb = in + (size_t)b * Cdim * Ndim;
  float* outb = out + (size_t)b * Cdim * Ndim;
#pragma unroll
  for (int i = threadIdx.y; i < 32; i += 8)
    tile[i][tx] = inb[(size_t)(c0 + i) * Ndim + (n0 + tx)];
  __syncthreads();
#pragma unroll
  for (int i = threadIdx.y; i < 32; i += 8)
    outb[(size_t)(n0 + i) * Cdim + (c0 + tx)] = tile[tx][i];
}

// -------- FPS prep: bbox -> morton -> in-LDS bitonic sort -> pair-SoA planes
// + 16-pt chunk AABB metadata (unchanged R9-R13).
__global__ __launch_bounds__(1024) void fps_prep_kernel(
    const float* __restrict__ xyz, float* __restrict__ pxx,
    float* __restrict__ pxy, float* __restrict__ pxz,
    unsigned* __restrict__ pxo, float* __restrict__ aabb) {
  const int b = blockIdx.x;
  const int t = threadIdx.x;
  const int lane = t & 63;
  const int w = t >> 6;
  const float* P = xyz + (size_t)b * kN * 3;
  __shared__ unsigned long long keys[kN];   // 128 KB
  __shared__ float sbb[6][16];

  float mnx = 3e38f, mny = 3e38f, mnz = 3e38f;
  float mxx = -3e38f, mxy = -3e38f, mxz = -3e38f;
  for (int p = t; p < kN; p += 1024) {
    float x = P[p * 3], y = P[p * 3 + 1], z = P[p * 3 + 2];
    mnx = fminf(mnx, x); mny = fminf(mny, y); mnz = fminf(mnz, z);
    mxx = fmaxf(mxx, x); mxy = fmaxf(mxy, y); mxz = fmaxf(mxz, z);
  }
#pragma unroll
  for (int off = 32; off >= 1; off >>= 1) {
    mnx = fminf(mnx, __shfl_xor(mnx, off, 64));
    mny = fminf(mny, __shfl_xor(mny, off, 64));
    mnz = fminf(mnz, __shfl_xor(mnz, off, 64));
    mxx = fmaxf(mxx, __shfl_xor(mxx, off, 64));
    mxy = fmaxf(mxy, __shfl_xor(mxy, off, 64));
    mxz = fmaxf(mxz, __shfl_xor(mxz, off, 64));
  }
  if (lane == 0) {
    sbb[0][w] = mnx; sbb[1][w] = mny; sbb[2][w] = mnz;
    sbb[3][w] = mxx; sbb[4][w] = mxy; sbb[5][w] = mxz;
  }
  __syncthreads();
  mnx = sbb[0][lane & 15]; mny = sbb[1][lane & 15]; mnz = sbb[2][lane & 15];
  mxx = sbb[3][lane & 15]; mxy = sbb[4][lane & 15]; mxz = sbb[5][lane & 15];
#pragma unroll
  for (int off = 8; off >= 1; off >>= 1) {
    mnx = fminf(mnx, __shfl_xor(mnx, off, 64));
    mny = fminf(mny, __shfl_xor(mny, off, 64));
    mnz = fminf(mnz, __shfl_xor(mnz, off, 64));
    mxx = fmaxf(mxx, __shfl_xor(mxx, off, 64));
    mxy = fmaxf(mxy, __shfl_xor(mxy, off, 64));
    mxz = fmaxf(mxz, __shfl_xor(mxz, off, 64));
  }
  __syncthreads();
  const float sx = 1023.0f / fmaxf(mxx - mnx, 1e-20f);
  const float sy = 1023.0f / fmaxf(mxy - mny, 1e-20f);
  const float sz = 1023.0f / fmaxf(mxz - mnz, 1e-20f);
  for (int p = t; p < kN; p += 1024) {
    float x = P[p * 3], y = P[p * 3 + 1], z = P[p * 3 + 2];
    int qx = (int)((x - mnx) * sx); qx = max(0, min(1023, qx));
    int qy = (int)((y - mny) * sy); qy = max(0, min(1023, qy));
    int qz = (int)((z - mnz) * sz); qz = max(0, min(1023, qz));
    unsigned mort = (expand10((unsigned)qx) << 2) |
                    (expand10((unsigned)qy) << 1) | expand10((unsigned)qz);
    keys[p] = ((unsigned long long)mort << 14) | (unsigned)p;
  }
  __syncthreads();
  for (unsigned k = 2; k <= (unsigned)kN; k <<= 1) {
    for (unsigned j = k >> 1; j > 0; j >>= 1) {
      for (int i = t; i < kN; i += 1024) {
        int l = i ^ (int)j;
        if (l > i) {
          unsigned long long a = keys[i], c = keys[l];
          bool asc = ((i & (int)k) == 0);
          if ((a > c) == asc) { keys[i] = c; keys[l] = a; }
        }
      }
      __syncthreads();
    }
  }
  float* FX = pxx + (size_t)b * kN;
  float* FY = pxy + (size_t)b * kN;
  float* FZ = pxz + (size_t)b * kN;
  unsigned* FO = pxo + (size_t)b * kN;
  for (int i = t; i < kN; i += 1024) {
    int o = (int)(keys[i] & 0x3FFFull);
    int c = i >> 4, j = i & 15;
    int fi = c * 16 + ((j & 7) << 1) + (j >> 3);
    FX[fi] = P[o * 3];
    FY[fi] = P[o * 3 + 1];
    FZ[fi] = P[o * 3 + 2];
    FO[fi] = 16383u - (unsigned)o;   // tie key: max(16383-o) == min orig
  }
  if (t < kNC16) {
    float amn = 3e38f, bmn = 3e38f, cmn = 3e38f;
    float amx = -3e38f, bmx = -3e38f, cmx = -3e38f;
    for (int kk = 0; kk < 16; kk++) {
      int o = (int)(keys[t * 16 + kk] & 0x3FFFull);
      float x = P[o * 3], y = P[o * 3 + 1], z = P[o * 3 + 2];
      amn = fminf(amn, x); amx = fmaxf(amx, x);
      bmn = fminf(bmn, y); bmx = fmaxf(bmx, y);
      cmn = fminf(cmn, z); cmx = fmaxf(cmx, z);
    }
    float* AB = aabb + (size_t)b * 6 * kNC16;
    AB[0 * kNC16 + t] = (amn + amx) * 0.5f;
    AB[1 * kNC16 + t] = (bmn + bmx) * 0.5f;
    AB[2 * kNC16 + t] = (cmn + cmx) * 0.5f;
    AB[3 * kNC16 + t] = (amx - amn) * 0.5f * 1.0001f + 2e-7f;
    AB[4 * kNC16 + t] = (bmx - bmn) * 0.5f * 1.0001f + 2e-7f;
    AB[5 * kNC16 + t] = (cmx - cmn) * 0.5f * 1.0001f + 2e-7f;
  }
}

// -------- FPS v12 (R13 verbatim — best known: 5273 us) ---------------------
__global__ __launch_bounds__(1024) void fps_kernel(
    const float* __restrict__ xyz,
    const float* __restrict__ pxx, const float* __restrict__ pxy,
    const float* __restrict__ pxz, const unsigned* __restrict__ pxo,
    const float* __restrict__ aabb, float* __restrict__ new_xyz) {
  const int b = blockIdx.x;
  const int t = threadIdx.x;
  const int lane = t & 63;
  const int w = t >> 6;
  const int grp = lane >> 3;
  const int sub8 = lane & 7;
  const int s0 = (w << 6) | lane;
  const float* P = xyz + (size_t)b * kN * 3;
  const f32x2* XP = (const f32x2*)(pxx + (size_t)b * kN);
  const f32x2* YP = (const f32x2*)(pxy + (size_t)b * kN);
  const f32x2* ZP = (const f32x2*)(pxz + (size_t)b * kN);
  const uint2* OP = (const uint2*)(pxo + (size_t)b * kN);

  __shared__ f32x2 dpair[kNP];        // 64 KB
  __shared__ uint2 M2[kNC16];         // 8 KB   {fbits, (tie<<10)|slot}
  __shared__ float4 CW[kNC16];        // 16 KB  winner coords
  __shared__ unsigned list_[16][64];  // 4 KB
  __shared__ unsigned whi[2][16], wlo[2][16];

  for (int i = t; i < kNP; i += 1024) dpair[i] = f32x2{1e10f, 1e10f};
  if (t < kNC16) M2[t] = uint2{__float_as_uint(1e10f), 0u};

  const int c0 = (lane << 4) | w;
  const float* AB = aabb + (size_t)b * 6 * kNC16;
  float ux = AB[c0], uy = AB[kNC16 + c0], uz = AB[2 * kNC16 + c0];
  float hx = AB[3 * kNC16 + c0], hy = AB[4 * kNC16 + c0], hz = AB[5 * kNC16 + c0];
  asm volatile("" : "+v"(ux), "+v"(uy), "+v"(uz), "+v"(hx), "+v"(hy), "+v"(hz));
  __syncthreads();

  float cx = P[0], cy = P[1], cz = P[2];

  for (int it = 0; it < kS; ++it) {
    if (t == 0) {
      float* o = new_xyz + ((size_t)b * kS + it) * 3;
      o[0] = cx; o[1] = cy; o[2] = cz;
    }
    {
      float txd = fmaxf(fabsf(cx - ux) - hx, 0.0f);
      float tyd = fmaxf(fabsf(cy - uy) - hy, 0.0f);
      float tzd = fmaxf(fabsf(cz - uz) - hz, 0.0f);
      float lb2 = txd * txd + tyd * tyd + tzd * tzd;
      float Mv = __uint_as_float(M2[s0].x);
      bool fail = !(lb2 >= Mv * 1.00001f + 1e-5f);
      unsigned long long fmask = __ballot(fail);
      int nf = (int)__popcll(fmask);
      if (fail) {
        int pos = (int)__popcll(fmask & ((1ull << lane) - 1ull));
        list_[w][pos] = (unsigned)lane;
      }
      const f32x2 ncx = f32x2{-cx, -cx};
      const f32x2 ncy = f32x2{-cy, -cy};
      const f32x2 ncz = f32x2{-cz, -cz};
      const int npass = (nf + 7) >> 3;
      for (int i = 0; i < npass; ++i) {
        int idx = min(i * 8 + grp, nf - 1);
        int cl = (int)list_[w][idx];
        int pb = (((cl << 4) | w) << 3) | sub8;
        f32x2 xp = XP[pb], yp = YP[pb], zp = ZP[pb];
        uint2 op = OP[pb];
        f32x2 dold = dpair[pb];
        f32x2 dx_, dy_, dz_, xx_, yy_, zz_, s1_, d2_;
        PK_ADD(dx_, xp, ncx);
        PK_ADD(dy_, yp, ncy);
        PK_ADD(dz_, zp, ncz);
        PK_MUL(xx_, dx_, dx_);
        PK_MUL(yy_, dy_, dy_);
        PK_MUL(zz_, dz_, dz_);
        PK_ADD(s1_, xx_, yy_);
        PK_ADD(d2_, s1_, zz_);
        f32x2 dk;
        dk.x = fminf(dold.x, d2_.x);
        dk.y = fminf(dold.y, d2_.y);
        dpair[pb] = dk;
        unsigned fa = __float_as_uint(dk.x), fbv = __float_as_uint(dk.y);
        unsigned mx = max8(max(fa, fbv));
        unsigned sa = (fa == mx) ? op.x : 0u;
        unsigned sb = (fbv == mx) ? op.y : 0u;
        unsigned m2v = max8(max(sa, sb));
        const int sl = (w << 6) | cl;
        if (sub8 == 0) M2[sl] = uint2{mx, (m2v << 10) | (unsigned)sl};
        if (op.x == m2v) CW[sl] = float4{xp.x, yp.x, zp.x, 0.0f};
        if (op.y == m2v) CW[sl] = float4{xp.y, yp.y, zp.y, 0.0f};
      }
    }
    {
      uint2 m = M2[s0];
      unsigned hi = m.x, lo = m.y;
      u64max_dpp<0xB1>(hi, lo);
      u64max_dpp<0x4E>(hi, lo);
      u64max_dpp<0x124>(hi, lo);
      u64max_dpp<0x128>(hi, lo);
      u64max_dpp<0x142>(hi, lo);
      u64max_dpp<0x143>(hi, lo);
      if (lane == 63) { whi[it & 1][w] = hi; wlo[it & 1][w] = lo; }
    }
    __syncthreads();
    {
      unsigned hi = whi[it & 1][lane & 15], lo = wlo[it & 1][lane & 15];
      u64max_dpp<0x121>(hi, lo);
      u64max_dpp<0x122>(hi, lo);
      u64max_dpp<0x124>(hi, lo);
      u64max_dpp<0x128>(hi, lo);
      float4 cw = CW[lo & 1023u];
      cx = cw.x; cy = cw.y; cz = cw.z;
    }
  }
}

// -------- ball query + MLP + direct output, one wave per query -------------
// Merges ball_query_kernel + group_mlp_kernel + final transpose (validated
// as R15/16's consumer path; here standalone, no synchronization). Saves the
// idxbuf round-trip, the aggT+transpose traffic, and two kernel launches.
// Block = 128 thr (2 waves) — the shape where this MLP historically compiles
// to VGPR~132 with zero scratch.
__global__ __launch_bounds__(128) void ballmlp_kernel(
    const float* __restrict__ xyz, const float* __restrict__ new_xyz,
    const float* __restrict__ featsT,
    const float* __restrict__ w1, const float* __restrict__ b1,
    const float* __restrict__ w2, const float* __restrict__ b2,
    const float* __restrict__ w3, const float* __restrict__ b3,
    const float* __restrict__ wa, const float* __restrict__ ba,
    const float* __restrict__ wc, const float* __restrict__ bc,
    float* __restrict__ out_feat, float* __restrict__ scores) {
  __shared__ __align__(16) float smem[2 * 2208];   // per-wave [32][68]+idxs
  const int wid = threadIdx.x >> 6;
  const int lane = threadIdx.x & 63;
  float* Xs = smem + wid * 2208;
  int* idxs = (int*)(Xs + 32 * 68);
  const int g = blockIdx.x * 2 + wid;   // query id, 0..8191
  const int b = g >> 12;
  const int q = g & (kS - 1);

  const float* nxp = new_xyz + ((size_t)b * kS + q) * 3;
  const float qx = nxp[0], qy = nxp[1], qz = nxp[2];
  const float* Pb = xyz + (size_t)b * kN * 3;
  const float* F = featsT + (size_t)b * kN * kC;

  // ---- ball query: first-32 in-radius, ascending original index ----
  {
    int cnt = 0;
    int first = -1;
    for (int j = 0; j < kN / 64; j++) {
      const int p = (j << 6) + lane;
      float dx = Pb[p * 3 + 0] - qx;
      float dy = Pb[p * 3 + 1] - qy;
      float dz = Pb[p * 3 + 2] - qz;
      float d = __fadd_rn(__fadd_rn(__fmul_rn(dx, dx), __fmul_rn(dy, dy)),
                          __fmul_rn(dz, dz));
      bool inb = d < 0.25f;
      unsigned long long m = __ballot(inb);
      if (first < 0 && m != 0ull) first = (j << 6) + (__ffsll(m) - 1);
      if (inb && cnt < kNS) {
        int r = cnt + (int)__popcll(m & ((1ull << lane) - 1ull));
        if (r < kNS) idxs[r] = p;
      }
      cnt += (int)__popcll(m);
      if (cnt >= kNS) break;
    }
    if (cnt < kNS) {
      int fill = (first >= 0) ? first : 0;
      if (lane >= cnt && lane < kNS) idxs[lane] = fill;
    }
  }
  // ---- gather ----
  if (lane < 32) {
    int p = idxs[lane];
    Xs[lane * 68 + 0] = Pb[p * 3 + 0] - qx;
    Xs[lane * 68 + 1] = Pb[p * 3 + 1] - qy;
    Xs[lane * 68 + 2] = Pb[p * 3 + 2] - qz;
  } else {
    Xs[(lane - 32) * 68 + 67] = 0.0f;   // pad column
  }
  for (int j = 0; j < 32; j++)
    Xs[j * 68 + 3 + lane] = F[(size_t)idxs[j] * kC + lane];
  // ---- layer 1: 67 -> 64, in-place ----
  {
    float wv[68];
#pragma unroll
    for (int k = 0; k < 67; k++) wv[k] = w1[lane * 67 + k];
    wv[67] = 0.0f;
    const float bias = b1[lane];
    for (int r = 0; r < 32; r++) {
      float acc = bias;
#pragma unroll
      for (int k4 = 0; k4 < 17; k4++) {
        float4 x = *(const float4*)&Xs[r * 68 + k4 * 4];
        acc += x.x * wv[k4 * 4 + 0] + x.y * wv[k4 * 4 + 1] +
               x.z * wv[k4 * 4 + 2] + x.w * wv[k4 * 4 + 3];
      }
      Xs[r * 68 + lane] = fmaxf(acc, 0.0f);
    }
  }
  // ---- layer 2: 64 -> 64, in-place ----
  {
    float wv[64];
#pragma unroll
    for (int k = 0; k < 64; k++) wv[k] = w2[lane * 64 + k];
    const float bias = b2[lane];
    for (int r = 0; r < 32; r++) {
      float acc = bias;
#pragma unroll
      for (int k4 = 0; k4 < 16; k4++) {
        float4 x = *(const float4*)&Xs[r * 68 + k4 * 4];
        acc += x.x * wv[k4 * 4 + 0] + x.y * wv[k4 * 4 + 1] +
               x.z * wv[k4 * 4 + 2] + x.w * wv[k4 * 4 + 3];
      }
      Xs[r * 68 + lane] = fmaxf(acc, 0.0f);
    }
  }
  // ---- layer 3: 64 -> 128 in two halves + maxpool (relu folded) ----
  float pph[2];
#pragma unroll
  for (int h = 0; h < 2; h++) {
    float wv[64];
#pragma unroll
    for (int k = 0; k < 64; k++) wv[k] = w3[(lane + 64 * h) * 64 + k];
    const float bias = b3[lane + 64 * h];
    float pm = 0.0f;
    for (int r = 0; r < 32; r++) {
      float acc = bias;
#pragma unroll
      for (int k4 = 0; k4 < 16; k4++) {
        float4 x = *(const float4*)&Xs[r * 68 + k4 * 4];
        acc += x.x * wv[k4 * 4 + 0] + x.y * wv[k4 * 4 + 1] +
               x.z * wv[k4 * 4 + 2] + x.w * wv[k4 * 4 + 3];
      }
      pm = fmaxf(pm, acc);
    }
    pph[h] = pm;
  }
  Xs[lane] = pph[0];
  Xs[64 + lane] = pph[1];
  // ---- aggregation 128->128 + relu, direct out_feat + score ----
  {
    float accA = ba[lane], accB = ba[lane + 64];
#pragma unroll
    for (int k4 = 0; k4 < 32; k4++) {
      float4 pv = *(const float4*)&Xs[k4 * 4];
      float4 wva = *(const float4*)&wa[lane * 128 + k4 * 4];
      float4 wvb = *(const float4*)&wa[(lane + 64) * 128 + k4 * 4];
      accA += pv.x * wva.x + pv.y * wva.y + pv.z * wva.z + pv.w * wva.w;
      accB += pv.x * wvb.x + pv.y * wvb.y + pv.z * wvb.z + pv.w * wvb.w;
    }
    float aggA = fmaxf(accA, 0.0f);
    float aggB = fmaxf(accB, 0.0f);
    out_feat[((size_t)b * 128 + lane) * kS + q] = aggA;
    out_feat[((size_t)b * 128 + 64 + lane) * kS + q] = aggB;
    float partial = aggA * wc[lane] + aggB * wc[lane + 64];
#pragma unroll
    for (int off = 32; off >= 1; off >>= 1)
      partial += __shfl_xor(partial, off, 64);
    if (lane == 0) scores[(size_t)b * kS + q] = partial + bc[0];
  }
}

extern "C" void kernel_launch(void* const* d_in, const int* in_sizes, int n_in,
                              void* d_out, int out_size, void* d_ws, size_t ws_size,
                              hipStream_t stream) {
  const float* xyz   = (const float*)d_in[0];
  const float* feats = (const float*)d_in[1];
  const float* w1 = (const float*)d_in[2];
  const float* b1 = (const float*)d_in[3];
  const float* w2 = (const float*)d_in[4];
  const float* b2 = (const float*)d_in[5];
  const float* w3 = (const float*)d_in[6];
  const float* b3 = (const float*)d_in[7];
  const float* wa = (const float*)d_in[8];
  const float* ba = (const float*)d_in[9];
  const float* wc = (const float*)d_in[10];
  const float* bc = (const float*)d_in[11];

  float* out_new_xyz = (float*)d_out;                               // B*S*3
  float* out_feat    = out_new_xyz + (size_t)kB * kS * 3;           // B*128*S
  float* out_scores  = out_feat + (size_t)kB * 128 * kS;            // B*S

  // ws layout: featsT [0,8MiB); prep buffers at [9MiB,...):
  // pxx/pxy/pxz/pxo 4x128KB, aabb 48KB.
  char* ws = (char*)d_ws;
  float* featsT = (float*)ws;
  float*    pxx = (float*)(ws + (size_t)9 * 1024 * 1024);
  float*    pxy = (float*)(ws + (size_t)9 * 1024 * 1024 + 128 * 1024);
  float*    pxz = (float*)(ws + (size_t)9 * 1024 * 1024 + 256 * 1024);
  unsigned* pxo = (unsigned*)(ws + (size_t)9 * 1024 * 1024 + 384 * 1024);
  float*   aabb = (float*)(ws + (size_t)9 * 1024 * 1024 + 512 * 1024);

  // features (B,C,N) -> featsT (B,N,C)
  transpose_kernel<<<dim3(kN / 32, kC / 32, kB), dim3(32, 8, 1), 0, stream>>>(
      feats, featsT, kC, kN);
  // FPS prep: morton sort + pair-SoA + chunk AABBs
  fps_prep_kernel<<<dim3(kB), dim3(1024), 0, stream>>>(
      xyz, pxx, pxy, pxz, pxo, aabb);
  // FPS -> new_xyz (chunk-pruned, exact; R13 structure)
  fps_kernel<<<dim3(kB), dim3(1024), 0, stream>>>(
      xyz, pxx, pxy, pxz, pxo, aabb, out_new_xyz);
  // ball query + MLP + direct transposed output (one wave per query)
  ballmlp_kernel<<<dim3(kB * kS / 2), dim3(128), 0, stream>>>(
      xyz, out_new_xyz, featsT,
      w1, b1, w2, b2, w3, b3, wa, ba, wc, bc, out_feat, out_scores);
}